// Round 1
// baseline (164.194 us; speedup 1.0000x reference)
//
#include <hip/hip_runtime.h>
#include <hip/hip_bf16.h>

#define NB 8192
#define ND 1024
#define NE 8

typedef unsigned short u16;
typedef __bf16 bf16x8 __attribute__((ext_vector_type(8)));
typedef float f32x4 __attribute__((ext_vector_type(4)));
typedef u16 u16x8 __attribute__((ext_vector_type(8)));

__device__ __forceinline__ u16 f2bf(float f) {
    union { float f; unsigned u; } v; v.f = f;
    unsigned r = v.u + 0x7fffu + ((v.u >> 16) & 1u);
    return (u16)(r >> 16);
}

// ---------------- K0: bucket by expert + init out with b2 ----------------
__global__ __launch_bounds__(1024) void k_prep(const int* __restrict__ ids,
    const float* __restrict__ b2, float* __restrict__ out,
    int* __restrict__ counts, int* __restrict__ offs, int* __restrict__ bucket)
{
    __shared__ int s_cnt[NE], s_off[NE];
    int t = threadIdx.x;
    if (t < NE) s_cnt[t] = 0;
    __syncthreads();
    #pragma unroll
    for (int i = 0; i < NB / 1024; ++i) {
        int b = t + i * 1024;
        int e = ids[b];
        atomicAdd(&s_cnt[e], 1);
        out[2 * b]     = b2[2 * e];
        out[2 * b + 1] = b2[2 * e + 1];
    }
    __syncthreads();
    if (t == 0) {
        int acc = 0;
        #pragma unroll
        for (int e2 = 0; e2 < NE; ++e2) {
            counts[e2] = s_cnt[e2];
            offs[e2] = acc;
            s_off[e2] = acc;
            acc += s_cnt[e2];
        }
    }
    __syncthreads();
    #pragma unroll
    for (int i = 0; i < NB / 1024; ++i) {
        int b = t + i * 1024;
        int e = ids[b];
        int pos = atomicAdd(&s_off[e], 1);
        bucket[pos] = b;
    }
}

// ---------------- K1: X fp32 -> bf16 ----------------
__global__ __launch_bounds__(256) void k_cvt_x(const float* __restrict__ X, u16* __restrict__ Xb) {
    long i = ((long)blockIdx.x * 256 + threadIdx.x) * 8;
    f32x4 a = *(const f32x4*)(X + i);
    f32x4 b = *(const f32x4*)(X + i + 4);
    u16x8 o;
    o[0] = f2bf(a[0]); o[1] = f2bf(a[1]); o[2] = f2bf(a[2]); o[3] = f2bf(a[3]);
    o[4] = f2bf(b[0]); o[5] = f2bf(b[1]); o[6] = f2bf(b[2]); o[7] = f2bf(b[3]);
    *(u16x8*)(Xb + i) = o;
}

// ---------------- K2: W1 fp32 [e][k][n] -> bf16 transposed [e][n][k] ----------------
__global__ __launch_bounds__(256) void k_cvt_w1(const float* __restrict__ W1, u16* __restrict__ W1t) {
    __shared__ float s[64][65];
    int bid = blockIdx.x;
    int e = bid >> 8;
    int tr = ((bid >> 4) & 15) << 6;  // k tile base
    int tc = (bid & 15) << 6;         // n tile base
    const float* src = W1 + (size_t)e * ND * ND;
    u16* dst = W1t + (size_t)e * ND * ND;
    int t = threadIdx.x;
    #pragma unroll
    for (int i = 0; i < 16; ++i) {
        int idx = i * 256 + t;
        int r = idx >> 6, c = idx & 63;
        s[c][r] = src[(size_t)(tr + r) * ND + tc + c];
    }
    __syncthreads();
    #pragma unroll
    for (int i = 0; i < 16; ++i) {
        int idx = i * 256 + t;
        int n = idx >> 6, k = idx & 63;
        dst[(size_t)(tc + n) * ND + tr + k] = f2bf(s[n][k]);
    }
}

// ---------------- K3: grouped GEMM (bf16 MFMA) + fused layer-2 epilogue ----------------
#define GLDS16(src, dst) __builtin_amdgcn_global_load_lds( \
    (const __attribute__((address_space(1))) void*)(src), \
    (__attribute__((address_space(3))) void*)(dst), 16, 0, 0)

__global__ __launch_bounds__(256) void k_gemm(
    const u16* __restrict__ Xb, const u16* __restrict__ W1t,
    const float* __restrict__ b1, const float* __restrict__ W2,
    const int* __restrict__ counts, const int* __restrict__ offs,
    const int* __restrict__ bucket, float* __restrict__ out)
{
    __shared__ u16 sA[2][128 * 32];
    __shared__ u16 sB[2][128 * 32];
    __shared__ int sRows[128];

    int bid = blockIdx.x;
    int e  = bid & 7;          // expert fastest -> pinned to XCD bid%8
    int nt = (bid >> 3) & 7;
    int mt = bid >> 6;

    int cnt = counts[e];
    if (mt * 128 >= cnt) return;
    int off = offs[e];
    int rem = cnt - mt * 128;

    int t = threadIdx.x;
    if (t < 128) {
        int r = mt * 128 + t;
        sRows[t] = bucket[off + (r < cnt ? r : 0)];
    }
    __syncthreads();

    int n0 = nt * 128;
    // staging: 512 chunks of 16B per tile; thread t owns chunks t and t+256
    int c0 = t, c1 = t + 256;
    int ar0 = c0 >> 2, as0 = (c0 & 3) * 8;
    int ar1 = c1 >> 2, as1 = (c1 & 3) * 8;
    const u16* a0p = Xb + (size_t)sRows[ar0] * ND + as0;
    const u16* a1p = Xb + (size_t)sRows[ar1] * ND + as1;
    const u16* b0p = W1t + ((size_t)e * ND + n0 + ar0) * ND + as0;
    const u16* b1p = W1t + ((size_t)e * ND + n0 + ar1) * ND + as1;
    int w = t >> 6;
    int l = t & 63;
    int lc = l & 15, kg = l >> 4;
    int wm = (w >> 1) * 64, wn = (w & 1) * 64;

    f32x4 acc[4][4] = {};

    char* sA0 = (char*)sA;  // [2][8192] bytes
    char* sB0 = (char*)sB;

    auto stage = [&](int buf, int k0) {
        GLDS16(a0p + k0, sA0 + buf * 8192 + w * 1024);
        GLDS16(a1p + k0, sA0 + buf * 8192 + 4096 + w * 1024);
        GLDS16(b0p + k0, sB0 + buf * 8192 + w * 1024);
        GLDS16(b1p + k0, sB0 + buf * 8192 + 4096 + w * 1024);
    };

    stage(0, 0);

    const int NKT = ND / 32;
    #pragma unroll 2
    for (int kt = 0; kt < NKT; ++kt) {
        int buf = kt & 1;
        if (kt + 1 < NKT) {
            stage(buf ^ 1, (kt + 1) * 32);
            asm volatile("s_waitcnt vmcnt(4)" ::: "memory");
        } else {
            asm volatile("s_waitcnt vmcnt(0)" ::: "memory");
        }
        asm volatile("s_barrier" ::: "memory");

        const char* Ab = sA0 + buf * 8192;
        const char* Bb = sB0 + buf * 8192;
        bf16x8 af[4], bfr[4];
        #pragma unroll
        for (int mf = 0; mf < 4; ++mf)
            af[mf] = *(const bf16x8*)(Ab + (wm + mf * 16 + lc) * 64 + kg * 16);
        #pragma unroll
        for (int nf = 0; nf < 4; ++nf)
            bfr[nf] = *(const bf16x8*)(Bb + (wn + nf * 16 + lc) * 64 + kg * 16);
        #pragma unroll
        for (int mf = 0; mf < 4; ++mf) {
            #pragma unroll
            for (int nf = 0; nf < 4; ++nf)
                acc[mf][nf] = __builtin_amdgcn_mfma_f32_16x16x32_bf16(af[mf], bfr[nf], acc[mf][nf], 0, 0, 0);
        }
        asm volatile("s_barrier" ::: "memory");
    }

    // fused layer 2: logits[b] += sum_n relu(h)*W2[e][n][:], reduced over this 128-col tile
    float b1v[4], w20[4], w21[4];
    #pragma unroll
    for (int nf = 0; nf < 4; ++nf) {
        int ncol = n0 + wn + nf * 16 + lc;
        b1v[nf] = b1[e * ND + ncol];
        w20[nf] = W2[((size_t)e * ND + ncol) * 2 + 0];
        w21[nf] = W2[((size_t)e * ND + ncol) * 2 + 1];
    }
    #pragma unroll
    for (int mf = 0; mf < 4; ++mf) {
        #pragma unroll
        for (int r = 0; r < 4; ++r) {
            float s0 = 0.f, s1 = 0.f;
            #pragma unroll
            for (int nf = 0; nf < 4; ++nf) {
                float h = acc[mf][nf][r] + b1v[nf];
                h = fmaxf(h, 0.f);
                s0 += h * w20[nf];
                s1 += h * w21[nf];
            }
            #pragma unroll
            for (int m = 8; m >= 1; m >>= 1) {
                s0 += __shfl_xor(s0, m, 64);
                s1 += __shfl_xor(s1, m, 64);
            }
            int row = wm + mf * 16 + kg * 4 + r;
            if (lc == 0 && row < rem) {
                int b = sRows[row];
                atomicAdd(&out[2 * b], s0);
                atomicAdd(&out[2 * b + 1], s1);
            }
        }
    }
}

extern "C" void kernel_launch(void* const* d_in, const int* in_sizes, int n_in,
                              void* d_out, int out_size, void* d_ws, size_t ws_size,
                              hipStream_t stream)
{
    const float* X   = (const float*)d_in[0];
    const int*   ids = (const int*)d_in[1];
    const float* W1  = (const float*)d_in[2];
    const float* b1  = (const float*)d_in[3];
    const float* W2  = (const float*)d_in[4];
    const float* b2  = (const float*)d_in[5];
    float* out = (float*)d_out;

    char* ws = (char*)d_ws;
    int* counts = (int*)ws;
    int* offs   = (int*)(ws + 32);
    int* bucket = (int*)(ws + 64);
    u16* Xb     = (u16*)(ws + 65536);
    u16* W1t    = (u16*)(ws + 65536 + (size_t)NB * ND * 2);

    k_prep<<<1, 1024, 0, stream>>>(ids, b2, out, counts, offs, bucket);
    k_cvt_x<<<(NB * ND / 8) / 256, 256, 0, stream>>>(X, Xb);
    k_cvt_w1<<<NE * 256, 256, 0, stream>>>(W1, W1t);
    k_gemm<<<(NB / 128) * 8 * 8, 256, 0, stream>>>(Xb, W1t, b1, W2, counts, offs, bucket, out);
}